// Round 8
// baseline (200.375 us; speedup 1.0000x reference)
//
#include <hip/hip_runtime.h>

#define NUSERS 100000
#define NITEMS 50000
#define NNODES 150000
#define DIM 64
#define E0 600000
#define E2 (2 * E0)
#define BB 8192
#define LW 1e-4f
#define NN16 150016
#define SPMM_B 2344    // ceil(NNODES*8 / 512)
#define LOSS3_B 512    // 16 batch elements per block

// ---- counting-sort CSR build (no device-scope atomics) ----
#define NBUCK 1172      // ceil(NNODES / 128): bucket = node >> 7
#define CHUNK_E 2048    // edges per chunk
#define CHUNKS 293      // ceil(E0 / CHUNK_E)
#define CPAD 320        // padded chunk stride in cnt matrix (bucket-major)
#define BCAP 3072       // LDS staging cap per bucket (max observed ~1.7K)

// ---- bf16 helpers (fp32 <-> packed bf16 pair in a uint) ----
__device__ __forceinline__ float bf_lo(unsigned u) { return __uint_as_float(u << 16); }
__device__ __forceinline__ float bf_hi(unsigned u) { return __uint_as_float(u & 0xffff0000u); }
__device__ __forceinline__ unsigned rne16(float x) {
  unsigned u = __float_as_uint(x);
  return (u + 0x7fffu + ((u >> 16) & 1u)) >> 16;
}
__device__ __forceinline__ unsigned pack2(float lo, float hi) {
  return rne16(lo) | (rne16(hi) << 16);
}

// NOTE (macro hygiene, R3/R6 compile failures): param not named x/y/z/w;
// all internals suffixed _ ; DSTIDX evaluated FIRST.
#define ACC8(X) do { \
    a0 += bf_lo((X).x); a1 += bf_hi((X).x); a2 += bf_lo((X).y); a3 += bf_hi((X).y); \
    a4 += bf_lo((X).z); a5 += bf_hi((X).z); a6 += bf_lo((X).w); a7 += bf_hi((X).w); \
  } while (0)

// 8 lanes per node row; sequential neighbors, 4x unrolled (4 gathers in flight).
#define SPMM_BODY(COLP, HQ, DSTP, DSTIDX)                                    \
  do {                                                                       \
    const int dsti_ = (DSTIDX);                                              \
    float a0 = 0, a1 = 0, a2 = 0, a3 = 0, a4 = 0, a5 = 0, a6 = 0, a7 = 0;    \
    int jend_ = st + dg;                                                     \
    int j_ = st;                                                             \
    for (; j_ + 4 <= jend_; j_ += 4) {                                       \
      int c0_ = (COLP)[j_], c1_ = (COLP)[j_ + 1];                            \
      int c2_ = (COLP)[j_ + 2], c3_ = (COLP)[j_ + 3];                        \
      uint4 x0_ = (HQ)[(size_t)c0_ * 8];                                     \
      uint4 x1_ = (HQ)[(size_t)c1_ * 8];                                     \
      uint4 x2_ = (HQ)[(size_t)c2_ * 8];                                     \
      uint4 x3_ = (HQ)[(size_t)c3_ * 8];                                     \
      ACC8(x0_); ACC8(x1_); ACC8(x2_); ACC8(x3_);                            \
    }                                                                        \
    if (j_ + 2 <= jend_) {                                                   \
      int c0_ = (COLP)[j_], c1_ = (COLP)[j_ + 1];                            \
      uint4 x0_ = (HQ)[(size_t)c0_ * 8];                                     \
      uint4 x1_ = (HQ)[(size_t)c1_ * 8];                                     \
      ACC8(x0_); ACC8(x1_);                                                  \
      j_ += 2;                                                               \
    }                                                                        \
    if (j_ < jend_) {                                                        \
      int c0_ = (COLP)[j_];                                                  \
      uint4 x0_ = (HQ)[(size_t)c0_ * 8];                                     \
      ACC8(x0_);                                                             \
    }                                                                        \
    float scl_ = dn * dn;                                                    \
    (DSTP)[dsti_] = make_uint4(pack2(a0 * scl_, a1 * scl_),                  \
                               pack2(a2 * scl_, a3 * scl_),                  \
                               pack2(a4 * scl_, a5 * scl_),                  \
                               pack2(a6 * scl_, a7 * scl_));                 \
  } while (0)

// Pass 1: per-chunk LDS histogram of bucket counts.
__global__ __launch_bounds__(256) void k_bcount(const int* __restrict__ eu,
                                                const int* __restrict__ ei,
                                                int* __restrict__ cnt) {
  __shared__ int h[NBUCK];
  for (int i = threadIdx.x; i < NBUCK; i += 256) h[i] = 0;
  __syncthreads();
  int c = blockIdx.x;
  int e0 = c * CHUNK_E;
  int e1 = min(e0 + CHUNK_E, E0);
  for (int e = e0 + threadIdx.x; e < e1; e += 256) {
    int u = eu[e];
    int it = NUSERS + ei[e];
    atomicAdd(&h[u >> 7], 1);
    atomicAdd(&h[it >> 7], 1);
  }
  __syncthreads();
  for (int i = threadIdx.x; i < NBUCK; i += 256) cnt[(size_t)i * CPAD + c] = h[i];
}

// Pass 2: per-bucket exclusive scan over chunks + bucket totals.
__global__ __launch_bounds__(256) void k_bscan1(int* __restrict__ cnt,
                                                int* __restrict__ btot) {
  int b = blockIdx.x * 4 + (threadIdx.x >> 6);   // grid = CHUNKS blocks (NBUCK/4)
  int lane = threadIdx.x & 63;
  int* row = cnt + (size_t)b * CPAD;
  int carry = 0;
  for (int c0 = 0; c0 < CHUNKS; c0 += 64) {
    int c = c0 + lane;
    int v = (c < CHUNKS) ? row[c] : 0;
    int s = v;
    #pragma unroll
    for (int m = 1; m < 64; m <<= 1) {
      int t = __shfl_up(s, m);
      if (lane >= m) s += t;
    }
    if (c < CHUNKS) row[c] = carry + s - v;      // exclusive within bucket
    carry += __shfl(s, 63);
  }
  if (lane == 63) btot[b] = carry;
}

// Pass 3: scatter directed edges into bucket regions. Each block privately
// scans btot -> bbase in LDS; block 0 publishes bbase. LDS atomics only.
__global__ __launch_bounds__(256) void k_bscatter(const int* __restrict__ eu,
                                                  const int* __restrict__ ei,
                                                  const int* __restrict__ cnt,
                                                  const int* __restrict__ btot,
                                                  int* __restrict__ bbase,
                                                  unsigned* __restrict__ pk) {
  __shared__ int S[1280];
  __shared__ int T[256];
  int bid = blockIdx.x, tid = threadIdx.x;
  for (int i = tid; i < 1280; i += 256) S[i] = (i < NBUCK) ? btot[i] : 0;
  __syncthreads();
  int b0 = tid * 5;
  int run = 0;
  #pragma unroll
  for (int k = 0; k < 5; k++) { run += S[b0 + k]; S[b0 + k] = run; }  // inclusive
  T[tid] = run;
  __syncthreads();
  for (int off = 1; off < 256; off <<= 1) {
    int t = 0;
    if (tid >= off) t = T[tid - off];
    __syncthreads();
    if (tid >= off) T[tid] += t;
    __syncthreads();
  }
  int texc = T[tid] - run;                        // exclusive across threads
  for (int k = 4; k >= 0; k--)                    // -> global exclusive, in place
    S[b0 + k] = texc + (k ? S[b0 + k - 1] : 0);
  if (bid == 0)
    for (int i = tid; i < NBUCK; i += 256) bbase[i] = S[i];
  __syncthreads();
  for (int i = tid; i < NBUCK; i += 256) S[i] += cnt[(size_t)i * CPAD + bid];
  __syncthreads();
  int e0 = bid * CHUNK_E, e1 = min(e0 + CHUNK_E, E0);
  for (int e = e0 + tid; e < e1; e += 256) {
    int u = eu[e];
    int it = NUSERS + ei[e];
    int s1 = atomicAdd(&S[u >> 7], 1);
    pk[s1] = ((unsigned)it << 7) | (unsigned)(u & 127);
    int s2 = atomicAdd(&S[it >> 7], 1);
    pk[s2] = ((unsigned)u << 7) | (unsigned)(it & 127);
  }
}

// Pass 4: one block per bucket (128 nodes). LDS histogram -> deg/ptr/dinv,
// LDS rank into lcol -> coalesced col stream-out; fused scaled-cast h0;
// NEW: bucket-local degree counting-sort -> perm (kills spmm wave divergence).
__global__ __launch_bounds__(256) void k_bucket_csr(
    const unsigned* __restrict__ pk, const int* __restrict__ btot,
    const int* __restrict__ bbase, int* __restrict__ deg, int* __restrict__ ptr,
    float* __restrict__ dinv, int* __restrict__ col, int* __restrict__ perm,
    const float4* __restrict__ Gu4, const float4* __restrict__ Gi4,
    uint2* __restrict__ h0) {
  __shared__ unsigned sitm[BCAP];
  __shared__ int lcol[BCAP];
  __shared__ int ldeg[128], lscan[128], lcnt[128];
  __shared__ float sdv[128];
  __shared__ int dh[64], ds2[64], dc2[64];
  int b = blockIdx.x;
  int tid = threadIdx.x;
  int base = bbase[b];
  int n = btot[b];
  for (int i = tid; i < n; i += 256)
    if (i < BCAP) sitm[i] = pk[base + i];
  if (tid < 128) { ldeg[tid] = 0; lcnt[tid] = 0; }
  if (tid < 64) { dh[tid] = 0; dc2[tid] = 0; }
  __syncthreads();
  for (int i = tid; i < n; i += 256) {
    unsigned p = (i < BCAP) ? sitm[i] : pk[base + i];
    atomicAdd(&ldeg[p & 127], 1);
  }
  __syncthreads();
  if (tid < 128) lscan[tid] = ldeg[tid];
  __syncthreads();
  for (int off = 1; off < 128; off <<= 1) {
    int t = 0;
    if (tid < 128 && tid >= off) t = lscan[tid - off];
    __syncthreads();
    if (tid < 128 && tid >= off) lscan[tid] += t;
    __syncthreads();
  }
  int node = b * 128 + tid;
  int myCls = -1;
  if (tid < 128) {
    int d = ldeg[tid];
    lscan[tid] -= d;               // -> exclusive (bucket-local)
    float dv = d > 0 ? rsqrtf((float)d) : 0.0f;
    sdv[tid] = dv;
    if (node < NNODES) {
      deg[node] = d;
      ptr[node] = base + lscan[tid];
      dinv[node] = dv;
      myCls = min(d, 63);
      atomicAdd(&dh[myCls], 1);    // degree-class histogram
    }
  }
  __syncthreads();
  // exclusive scan of 64 degree-class bins (wave 0)
  if (tid < 64) {
    int v = dh[tid];
    int s = v;
    #pragma unroll
    for (int m = 1; m < 64; m <<= 1) {
      int t = __shfl_up(s, m);
      if (tid >= m) s += t;
    }
    ds2[tid] = s - v;
  }
  __syncthreads();
  // rank nodes by degree class -> perm (dense: every bucket's real nodes)
  if (myCls >= 0) {
    int pos = ds2[myCls] + atomicAdd(&dc2[myCls], 1);
    perm[b * 128 + pos] = node;
  }
  for (int i = tid; i < n; i += 256) {
    unsigned p = (i < BCAP) ? sitm[i] : pk[base + i];
    int dl = p & 127;
    int nb = (int)(p >> 7);                // neighbor global id
    int dnode = b * 128 + dl;
    int val = (dnode < NUSERS) ? nb - NUSERS : nb;   // opposite-half-local id
    int rel = lscan[dl] + atomicAdd(&lcnt[dl], 1);
    if (rel < BCAP) lcol[rel] = val;
    else col[base + rel] = val;            // overflow fallback (rare/never)
  }
  __syncthreads();
  int nf = min(n, BCAP);
  for (int i = tid; i < nf; i += 256) col[base + i] = lcol[i];
  // scaled cast: h0 = bf16(dinv * G) for this bucket's 128 nodes
  for (int w = tid; w < 128 * 16; w += 256) {
    int nl = w >> 4, q = w & 15;
    int nd = b * 128 + nl;
    if (nd < NNODES) {
      float dv = sdv[nl];
      float4 v = (nd < NUSERS) ? Gu4[(size_t)nd * 16 + q]
                               : Gi4[(size_t)(nd - NUSERS) * 16 + q];
      h0[(size_t)nd * 16 + q] =
          make_uint2(pack2(dv * v.x, dv * v.y), pack2(dv * v.z, dv * v.w));
    }
  }
}

// Scaled-space SpMM: s_out(n) = dinv(n)^2 * sum_{c in N(n)} s_in(c).
// Processes nodes in degree-sorted order (perm) so each wave's 8 node-groups
// have near-equal degree -> loop trips ~= own degree, not max-of-8.
__global__ __launch_bounds__(512) void k_spmm2(
    const int* __restrict__ perm,
    const int* __restrict__ ptr, const int* __restrict__ deg,
    const int* __restrict__ col, const float* __restrict__ dinv,
    const uint4* __restrict__ h, uint4* __restrict__ hout) {
  int t = blockIdx.x * 512 + threadIdx.x;
  int i = t >> 3;
  int q = t & 7;
  if (i >= NNODES) return;
  int g = perm[i];
  const uint4* hq = ((g < NUSERS) ? h + (size_t)NUSERS * 8 : h) + q;
  int st = ptr[g], dg = deg[g];
  float dn = dinv[g];
  SPMM_BODY(col, hq, hout, (size_t)g * 8 + q);
}

// Fused: per-block layer-3 SpMM for its own 16 batch elements (48 nodes)
// into 6KB LDS, then gather + layer sum + BPR loss. Block-local dep only.
__global__ __launch_bounds__(256) void k_loss3(
    const int* __restrict__ usr, const int* __restrict__ pos,
    const int* __restrict__ neg, const int* __restrict__ ptr,
    const int* __restrict__ deg, const int* __restrict__ col,
    const float* __restrict__ dinv,
    const float4* __restrict__ Gu4, const float4* __restrict__ Gi4,
    const uint4* __restrict__ h2v, const uint2* __restrict__ h1u,
    const uint2* __restrict__ h2u, float* __restrict__ bpart) {
  __shared__ uint4 sh3[48 * 8];    // 48 node rows x 128B = 6KB
  __shared__ float sL[4], sR[4];
  int bid = blockIdx.x, tid = threadIdx.x;

  // Phase 1: s3 for this block's 48 nodes (8 lanes per node row)
  for (int t = tid; t < 48 * 8; t += 256) {
    int s = t >> 3, q = t & 7;
    int bb = s / 3, role = s - bb * 3;
    int b = bid * 16 + bb;
    int g, coff;
    if (role == 0) { g = usr[b]; coff = NUSERS; }
    else if (role == 1) { g = NUSERS + pos[b]; coff = 0; }
    else { g = NUSERS + neg[b]; coff = 0; }
    const uint4* hq = h2v + (size_t)coff * 8 + q;
    int st = ptr[g], dg = deg[g];
    float dn = dinv[g];
    SPMM_BODY(col, hq, sh3, s * 8 + q);
  }
  __syncthreads();

  // Phase 2: loss; 16 lanes per batch element.
  const uint2* sh3u = (const uint2*)sh3;
  int wid = tid >> 6, lane = tid & 63;
  int bb = tid >> 4, q = tid & 15;
  int b = bid * 16 + bb;
  const float sc = 0.25f;
  int iu = usr[b], ip = pos[b], ig = neg[b];
  float sdu = sqrtf((float)deg[iu]);
  float sdp = sqrtf((float)deg[NUSERS + ip]);
  float sdn = sqrtf((float)deg[NUSERS + ig]);
  size_t ou = (size_t)iu * 16 + q;
  size_t op = ((size_t)NUSERS + ip) * 16 + q;
  size_t on = ((size_t)NUSERS + ig) * 16 + q;
  float4 u = Gu4[ou];
  float4 p = Gi4[(size_t)ip * 16 + q];
  float4 g = Gi4[(size_t)ig * 16 + q];
  float4 su = {0, 0, 0, 0}, sp = {0, 0, 0, 0}, sg = {0, 0, 0, 0};
  uint2 v;
  v = h1u[ou]; su.x += bf_lo(v.x); su.y += bf_hi(v.x); su.z += bf_lo(v.y); su.w += bf_hi(v.y);
  v = h2u[ou]; su.x += bf_lo(v.x); su.y += bf_hi(v.x); su.z += bf_lo(v.y); su.w += bf_hi(v.y);
  v = sh3u[(size_t)(bb * 3 + 0) * 16 + q];
  su.x += bf_lo(v.x); su.y += bf_hi(v.x); su.z += bf_lo(v.y); su.w += bf_hi(v.y);
  v = h1u[op]; sp.x += bf_lo(v.x); sp.y += bf_hi(v.x); sp.z += bf_lo(v.y); sp.w += bf_hi(v.y);
  v = h2u[op]; sp.x += bf_lo(v.x); sp.y += bf_hi(v.x); sp.z += bf_lo(v.y); sp.w += bf_hi(v.y);
  v = sh3u[(size_t)(bb * 3 + 1) * 16 + q];
  sp.x += bf_lo(v.x); sp.y += bf_hi(v.x); sp.z += bf_lo(v.y); sp.w += bf_hi(v.y);
  v = h1u[on]; sg.x += bf_lo(v.x); sg.y += bf_hi(v.x); sg.z += bf_lo(v.y); sg.w += bf_hi(v.y);
  v = h2u[on]; sg.x += bf_lo(v.x); sg.y += bf_hi(v.x); sg.z += bf_lo(v.y); sg.w += bf_hi(v.y);
  v = sh3u[(size_t)(bb * 3 + 2) * 16 + q];
  sg.x += bf_lo(v.x); sg.y += bf_hi(v.x); sg.z += bf_lo(v.y); sg.w += bf_hi(v.y);
  u.x = (u.x + sdu * su.x) * sc; u.y = (u.y + sdu * su.y) * sc;
  u.z = (u.z + sdu * su.z) * sc; u.w = (u.w + sdu * su.w) * sc;
  p.x = (p.x + sdp * sp.x) * sc; p.y = (p.y + sdp * sp.y) * sc;
  p.z = (p.z + sdp * sp.z) * sc; p.w = (p.w + sdp * sp.w) * sc;
  g.x = (g.x + sdn * sg.x) * sc; g.y = (g.y + sdn * sg.y) * sc;
  g.z = (g.z + sdn * sg.z) * sc; g.w = (g.w + sdn * sg.w) * sc;
  float dp = u.x * p.x + u.y * p.y + u.z * p.z + u.w * p.w;
  float dn = u.x * g.x + u.y * g.y + u.z * g.z + u.w * g.w;
  float rg = u.x * u.x + u.y * u.y + u.z * u.z + u.w * u.w
           + p.x * p.x + p.y * p.y + p.z * p.z + p.w * p.w
           + g.x * g.x + g.y * g.y + g.z * g.z + g.w * g.w;
  #pragma unroll
  for (int m = 1; m <= 8; m <<= 1) {
    dp += __shfl_xor(dp, m);
    dn += __shfl_xor(dn, m);
    rg += __shfl_xor(rg, m);
  }
  float accL = 0.0f, accR = 0.0f;
  if (q == 0) {
    float diff = dp - dn;
    accL = -(fminf(diff, 0.0f) - log1pf(expf(-fabsf(diff))));
    accR = rg;
  }
  accL += __shfl_xor(accL, 16); accR += __shfl_xor(accR, 16);
  accL += __shfl_xor(accL, 32); accR += __shfl_xor(accR, 32);
  if (lane == 0) { sL[wid] = accL; sR[wid] = accR; }
  __syncthreads();
  if (tid == 0) {
    bpart[bid] = sL[0] + sL[1] + sL[2] + sL[3];
    bpart[LOSS3_B + bid] = sR[0] + sR[1] + sR[2] + sR[3];
  }
}

__global__ void k_final(const float* __restrict__ bpart, float* __restrict__ out) {
  int lane = threadIdx.x;
  float l = 0.0f, r = 0.0f;
  #pragma unroll
  for (int i = 0; i < LOSS3_B; i += 64) {
    l += bpart[lane + i];
    r += bpart[LOSS3_B + lane + i];
  }
  for (int off = 32; off > 0; off >>= 1) {
    l += __shfl_down(l, off);
    r += __shfl_down(r, off);
  }
  if (lane == 0) out[0] = l * (1.0f / BB) + LW * 0.5f * r * (1.0f / BB);
}

extern "C" void kernel_launch(void* const* d_in, const int* in_sizes, int n_in,
                              void* d_out, int out_size, void* d_ws, size_t ws_size,
                              hipStream_t stream) {
  const float* Gu = (const float*)d_in[0];
  const float* Gi = (const float*)d_in[1];
  const int* eu  = (const int*)d_in[2];
  const int* ei  = (const int*)d_in[3];
  const int* usr = (const int*)d_in[4];
  const int* pos = (const int*)d_in[5];
  const int* neg = (const int*)d_in[6];
  float* out = (float*)d_out;

  // Workspace: deg/ptr/dinv + col + h0..h2 + build scratch + bpart + perm.
  int* deg    = (int*)d_ws;                  // NN16
  int* ptr    = deg + NN16;                  // NN16
  float* dinv = (float*)(ptr + NN16);        // NN16
  int* col    = (int*)(dinv + NN16);         // E2
  uint2* h0   = (uint2*)(col + E2);          // NNODES*16 uint2 each (19.2 MB)
  uint2* h1   = h0 + (size_t)NNODES * 16;
  uint2* h2   = h1 + (size_t)NNODES * 16;
  uint2* h3   = h2 + (size_t)NNODES * 16;    // build scratch region
  float* bpart = (float*)(h3 + (size_t)NNODES * 16);  // 2*LOSS3_B
  int* perm   = (int*)(bpart + 2 * LOSS3_B); // NNODES (degree-sorted order)

  unsigned* pk = (unsigned*)h1;              // E2 (scattered directed edges)
  int* cnt     = (int*)h2;                   // NBUCK * CPAD
  int* btot    = (int*)h3;                   // NBUCK
  int* bbase   = btot + 1280;                // NBUCK

  const float4* Gu4 = (const float4*)Gu;
  const float4* Gi4 = (const float4*)Gi;

  // CSR build via two-level counting sort — zero device-scope atomics.
  k_bcount<<<CHUNKS, 256, 0, stream>>>(eu, ei, cnt);
  k_bscan1<<<CHUNKS, 256, 0, stream>>>(cnt, btot);
  k_bscatter<<<CHUNKS, 256, 0, stream>>>(eu, ei, cnt, btot, bbase, pk);
  k_bucket_csr<<<NBUCK, 256, 0, stream>>>(pk, btot, bbase, deg, ptr, dinv, col,
                                          perm, Gu4, Gi4, h0);

  k_spmm2<<<SPMM_B, 512, 0, stream>>>(perm, ptr, deg, col, dinv,
                                      (const uint4*)h0, (uint4*)h1);
  k_spmm2<<<SPMM_B, 512, 0, stream>>>(perm, ptr, deg, col, dinv,
                                      (const uint4*)h1, (uint4*)h2);

  k_loss3<<<LOSS3_B, 256, 0, stream>>>(usr, pos, neg, ptr, deg, col, dinv,
                                       Gu4, Gi4, (const uint4*)h2,
                                       (const uint2*)h1, (const uint2*)h2, bpart);
  k_final<<<1, 64, 0, stream>>>(bpart, out);
}